// Round 6
// baseline (239.212 us; speedup 1.0000x reference)
//
#include <hip/hip_runtime.h>
#include <hip/hip_bf16.h>
#include <math.h>

#define NTOT  8192
#define DIM   512
#define BATCH (NTOT/2)
#define TEMP_INV 5.0f   // 1/0.2
#define TTILE 64                      // 8192 / 128 tiles per side
#define NBLK  (TTILE*(TTILE+1)/2)     // 2080 upper-triangle tiles

typedef __attribute__((ext_vector_type(8))) short bf16x8;
typedef __attribute__((ext_vector_type(4))) float f32x4;

// column-major triangle decode: t = bj*(bj+1)/2 + bi, bi <= bj.
__device__ __forceinline__ void decode_tile(int t, int& bi, int& bj)
{
    int b = (int)((sqrtf(8.0f * (float)t + 1.0f) - 1.0f) * 0.5f);
    while ((b + 1) * (b + 2) / 2 <= t) ++b;
    while (b * (b + 1) / 2 > t)       --b;
    bj = b;
    bi = t - b * (b + 1) / 2;
}

__device__ __forceinline__ unsigned int pack_bf16_2(float a, float b)
{
    __hip_bfloat16 ha = __float2bfloat16(a), hb = __float2bfloat16(b);
    unsigned short ua, ub;
    __builtin_memcpy(&ua, &ha, 2); __builtin_memcpy(&ub, &hb, 2);
    return (unsigned int)ua | ((unsigned int)ub << 16);
}
__device__ __forceinline__ float us2f(unsigned short u)
{
    __hip_bfloat16 h; __builtin_memcpy(&h, &u, 2);
    return __bfloat162float(h);
}

// ---------------- normalize: one wave per row ----------------
__global__ __launch_bounds__(256)
void normalize_k(const float* __restrict__ z, __hip_bfloat16* __restrict__ zn)
{
    const int lane = threadIdx.x & 63, wave = threadIdx.x >> 6;
    const int row  = blockIdx.x * 4 + wave;
    const float4* zr = (const float4*)(z + (size_t)row * DIM);
    const float4 a = zr[lane];
    const float4 b = zr[lane + 64];
    float ss = a.x*a.x + a.y*a.y + a.z*a.z + a.w*a.w
             + b.x*b.x + b.y*b.y + b.z*b.z + b.w*b.w;
    #pragma unroll
    for (int off = 1; off < 64; off <<= 1) ss += __shfl_xor(ss, off);
    const float inv = 1.0f / fmaxf(sqrtf(ss), 1e-12f);
    uint2* zo = (uint2*)(zn + (size_t)row * DIM);
    uint2 o0, o1;
    o0.x = pack_bf16_2(a.x * inv, a.y * inv);
    o0.y = pack_bf16_2(a.z * inv, a.w * inv);
    o1.x = pack_bf16_2(b.x * inv, b.y * inv);
    o1.y = pack_bf16_2(b.z * inv, b.w * inv);
    zo[lane]      = o0;
    zo[lane + 64] = o1;
}

// ---------------- transpose zn -> znT (512 x 8192) + column sums S ----------------
__global__ __launch_bounds__(256)
void trans_colsum_k(const __hip_bfloat16* __restrict__ zn,
                    __hip_bfloat16* __restrict__ znT,
                    float* __restrict__ S)
{
    __shared__ unsigned short tile[64][72];   // +8 pad breaks bank alignment
    const int t  = threadIdx.x;
    const int r0 = blockIdx.x * 64, c0 = blockIdx.y * 64;
    #pragma unroll
    for (int v = 0; v < 2; ++v) {
        const int r  = v * 32 + (t >> 3);
        const int cb = (t & 7) * 8;
        *(bf16x8*)&tile[r][cb] = *(const bf16x8*)(zn + (size_t)(r0 + r) * DIM + c0 + cb);
    }
    __syncthreads();
    #pragma unroll
    for (int v = 0; v < 2; ++v) {
        const int cl = v * 32 + (t >> 3);     // local column (dim index)
        const int rb = (t & 7) * 8;           // local row base
        bf16x8 w;
        float s = 0.f;
        #pragma unroll
        for (int e = 0; e < 8; ++e) {
            const unsigned short u = tile[rb + e][cl];
            w[e] = (short)u;
            s += us2f(u);
        }
        *(bf16x8*)(znT + (size_t)(c0 + cl) * NTOT + r0 + rb) = w;
        s += __shfl_xor(s, 1, 8);
        s += __shfl_xor(s, 2, 8);
        s += __shfl_xor(s, 4, 8);
        if ((t & 7) == 0) atomicAdd(&S[c0 + cl], s);
    }
}

// ---------------- Gram: G = Zn^T Zn via znT (both operands row-major, K=8192) ----------------
// split-K: blockIdx.z selects a 512-wide K chunk; fp32 atomicAdd into G32.
__global__ __launch_bounds__(256, 4)
void gram_k(const __hip_bfloat16* __restrict__ znT, float* __restrict__ G32)
{
    __shared__ unsigned short Asm[8192];   // 16 KB: 128 rows x 64 k, frag order
    __shared__ unsigned short Bsm[8192];
    const int tid = threadIdx.x, wave = tid >> 6, lane = tid & 63;
    const int f_l = lane & 15, q_l = lane >> 4;
    const int a0 = blockIdx.x * 128, b0 = blockIdx.y * 128;
    const int kbase = blockIdx.z * 512;
    const int wr = wave >> 1, wc = wave & 1;

    auto issue = [&](int k0) {
        #pragma unroll
        for (int s4 = 0; s4 < 4; ++s4) {
            const int seg = wave * 4 + s4, rowseg = seg >> 1, kh = seg & 1;
            const int gk  = kbase + k0 + kh * 32 + q_l * 8;
            const __hip_bfloat16* ga = znT + (size_t)(a0 + rowseg * 16 + f_l) * NTOT + gk;
            const __hip_bfloat16* gb = znT + (size_t)(b0 + rowseg * 16 + f_l) * NTOT + gk;
            __builtin_amdgcn_global_load_lds(
                (const __attribute__((address_space(1))) unsigned int*)ga,
                (__attribute__((address_space(3))) unsigned int*)(Asm + seg * 512 + lane * 8), 16, 0, 0);
            __builtin_amdgcn_global_load_lds(
                (const __attribute__((address_space(1))) unsigned int*)gb,
                (__attribute__((address_space(3))) unsigned int*)(Bsm + seg * 512 + lane * 8), 16, 0, 0);
        }
    };

    f32x4 acc[4][4];
    #pragma unroll
    for (int r = 0; r < 4; ++r)
        #pragma unroll
        for (int c = 0; c < 4; ++c) acc[r][c] = (f32x4){0.f,0.f,0.f,0.f};

    issue(0);
    for (int ki = 0; ki < 8; ++ki) {
        __syncthreads();
        bf16x8 af[4][2], bfr[4][2];
        #pragma unroll
        for (int r = 0; r < 4; ++r)
            #pragma unroll
            for (int h = 0; h < 2; ++h)
                af[r][h] = *(const bf16x8*)(Asm + ((wr*4+r)*2+h)*512 + lane*8);
        #pragma unroll
        for (int c = 0; c < 4; ++c)
            #pragma unroll
            for (int h = 0; h < 2; ++h)
                bfr[c][h] = *(const bf16x8*)(Bsm + ((wc*4+c)*2+h)*512 + lane*8);
        __syncthreads();
        if (ki < 7) issue((ki + 1) * 64);
        #pragma unroll
        for (int h = 0; h < 2; ++h)
            #pragma unroll
            for (int r = 0; r < 4; ++r)
                #pragma unroll
                for (int c = 0; c < 4; ++c)
                    acc[r][c] = __builtin_amdgcn_mfma_f32_16x16x32_bf16(af[r][h], bfr[c][h], acc[r][c], 0,0,0);
    }
    // C/D: row (a-dim) = q_l*4+u, col (b-dim) = f_l
    #pragma unroll
    for (int r = 0; r < 4; ++r)
        #pragma unroll
        for (int c = 0; c < 4; ++c)
            #pragma unroll
            for (int u = 0; u < 4; ++u)
                atomicAdd(&G32[(size_t)(a0 + wr*64 + r*16 + q_l*4 + u) * DIM
                               + b0 + wc*64 + c*16 + f_l], acc[r][c][u]);
}

// ---------------- G32 fp32 -> Gbf bf16 ----------------
__global__ __launch_bounds__(256)
void convg_k(const float* __restrict__ G32, __hip_bfloat16* __restrict__ Gbf)
{
    const int idx = blockIdx.x * 256 + threadIdx.x;   // float4 index
    const float4 g = ((const float4*)G32)[idx];
    uint2 o; o.x = pack_bf16_2(g.x, g.y); o.y = pack_bf16_2(g.z, g.w);
    ((uint2*)Gbf)[idx] = o;
}

// ---------------- q_i = zn_i^T G zn_i and rowsum_i = zn_i . S (fused GEMM) ----------------
// C = Zn * G (G symmetric, row-major both): per block 128 rows x 128-dim slab, K=512.
__global__ __launch_bounds__(256, 4)
void qrow_k(const __hip_bfloat16* __restrict__ zn,
            const __hip_bfloat16* __restrict__ Gbf,
            const float* __restrict__ S,
            float* __restrict__ rowsum,
            float* __restrict__ q)
{
    __shared__ unsigned short Asm[8192];
    __shared__ unsigned short Bsm[8192];
    const int tid = threadIdx.x, wave = tid >> 6, lane = tid & 63;
    const int f_l = lane & 15, q_l = lane >> 4;
    const int C0 = blockIdx.x * 128;   // dim slab (rows of G)
    const int R0 = blockIdx.y * 128;   // zn rows
    const int wr = wave >> 1, wc = wave & 1;

    auto issue = [&](int k0) {
        #pragma unroll
        for (int s4 = 0; s4 < 4; ++s4) {
            const int seg = wave * 4 + s4, rowseg = seg >> 1, kh = seg & 1;
            const int gk  = k0 + kh * 32 + q_l * 8;
            const __hip_bfloat16* ga = zn  + (size_t)(R0 + rowseg * 16 + f_l) * DIM + gk;
            const __hip_bfloat16* gb = Gbf + (size_t)(C0 + rowseg * 16 + f_l) * DIM + gk;
            __builtin_amdgcn_global_load_lds(
                (const __attribute__((address_space(1))) unsigned int*)ga,
                (__attribute__((address_space(3))) unsigned int*)(Asm + seg * 512 + lane * 8), 16, 0, 0);
            __builtin_amdgcn_global_load_lds(
                (const __attribute__((address_space(1))) unsigned int*)gb,
                (__attribute__((address_space(3))) unsigned int*)(Bsm + seg * 512 + lane * 8), 16, 0, 0);
        }
    };

    f32x4 acc[4][4];
    #pragma unroll
    for (int r = 0; r < 4; ++r)
        #pragma unroll
        for (int c = 0; c < 4; ++c) acc[r][c] = (f32x4){0.f,0.f,0.f,0.f};

    issue(0);
    for (int ki = 0; ki < 8; ++ki) {
        __syncthreads();
        bf16x8 af[4][2], bfr[4][2];
        #pragma unroll
        for (int r = 0; r < 4; ++r)
            #pragma unroll
            for (int h = 0; h < 2; ++h)
                af[r][h] = *(const bf16x8*)(Asm + ((wr*4+r)*2+h)*512 + lane*8);
        #pragma unroll
        for (int c = 0; c < 4; ++c)
            #pragma unroll
            for (int h = 0; h < 2; ++h)
                bfr[c][h] = *(const bf16x8*)(Bsm + ((wc*4+c)*2+h)*512 + lane*8);
        __syncthreads();
        if (ki < 7) issue((ki + 1) * 64);
        #pragma unroll
        for (int h = 0; h < 2; ++h)
            #pragma unroll
            for (int r = 0; r < 4; ++r)
                #pragma unroll
                for (int c = 0; c < 4; ++c)
                    acc[r][c] = __builtin_amdgcn_mfma_f32_16x16x32_bf16(af[r][h], bfr[c][h], acc[r][c], 0,0,0);
    }

    // epilogue: q_i partial = sum_n C[i][n]*zn[i][n]; rowsum_i partial = sum_n zn[i][n]*S[n]
    float Sn[4];
    #pragma unroll
    for (int c = 0; c < 4; ++c) Sn[c] = S[C0 + wc*64 + c*16 + f_l];
    #pragma unroll
    for (int r = 0; r < 4; ++r) {
        float qp[4] = {0,0,0,0}, rp[4] = {0,0,0,0};
        #pragma unroll
        for (int c = 0; c < 4; ++c) {
            const int n = C0 + wc*64 + c*16 + f_l;
            #pragma unroll
            for (int u = 0; u < 4; ++u) {
                const int i = R0 + wr*64 + r*16 + q_l*4 + u;
                const float w = __bfloat162float(zn[(size_t)i * DIM + n]);
                qp[u] += acc[r][c][u] * w;
                rp[u] += w * Sn[c];
            }
        }
        #pragma unroll
        for (int off = 1; off < 16; off <<= 1) {
            #pragma unroll
            for (int u = 0; u < 4; ++u) {
                qp[u] += __shfl_xor(qp[u], off);
                rp[u] += __shfl_xor(rp[u], off);
            }
        }
        if (f_l == 0) {
            #pragma unroll
            for (int u = 0; u < 4; ++u) {
                const int i = R0 + wr*64 + r*16 + q_l*4 + u;
                atomicAdd(&q[i], qp[u]);
                atomicAdd(&rowsum[i], rp[u]);
            }
        }
    }
}

// ---------------- sim pass: single triangle MFMA pass, neg-sum in epilogue ----------------
__global__ __launch_bounds__(256, 4)
void sim_neg_k(const __hip_bfloat16* __restrict__ zn,
               const int*   __restrict__ labels,
               const float* __restrict__ rowsum,
               const float* __restrict__ q,
               double* __restrict__ neg_acc)
{
    __shared__ unsigned short Asm[8192];   // 16 KB, frag order
    __shared__ unsigned short Bsm[8192];
    __shared__ float redbuf[4];
    const int tid = threadIdx.x, wave = tid >> 6, lane = tid & 63;
    const int f_l = lane & 15, q_l = lane >> 4;
    int bi, bj;
    decode_tile(blockIdx.x, bi, bj);
    const int R0 = bi * 128, C0 = bj * 128;
    const int wr = wave >> 1, wc = wave & 1;

    auto issue = [&](int k0) {
        #pragma unroll
        for (int s4 = 0; s4 < 4; ++s4) {
            const int seg = wave * 4 + s4, rowseg = seg >> 1, kh = seg & 1;
            const int gk  = k0 + kh * 32 + q_l * 8;
            const __hip_bfloat16* ga = zn + (size_t)(R0 + rowseg * 16 + f_l) * DIM + gk;
            const __hip_bfloat16* gb = zn + (size_t)(C0 + rowseg * 16 + f_l) * DIM + gk;
            __builtin_amdgcn_global_load_lds(
                (const __attribute__((address_space(1))) unsigned int*)ga,
                (__attribute__((address_space(3))) unsigned int*)(Asm + seg * 512 + lane * 8), 16, 0, 0);
            __builtin_amdgcn_global_load_lds(
                (const __attribute__((address_space(1))) unsigned int*)gb,
                (__attribute__((address_space(3))) unsigned int*)(Bsm + seg * 512 + lane * 8), 16, 0, 0);
        }
    };

    f32x4 acc[4][4];
    #pragma unroll
    for (int r = 0; r < 4; ++r)
        #pragma unroll
        for (int c = 0; c < 4; ++c) acc[r][c] = (f32x4){0.f,0.f,0.f,0.f};

    issue(0);
    for (int ki = 0; ki < 8; ++ki) {
        __syncthreads();
        bf16x8 af[4][2], bfr[4][2];
        #pragma unroll
        for (int r = 0; r < 4; ++r)
            #pragma unroll
            for (int h = 0; h < 2; ++h)
                af[r][h] = *(const bf16x8*)(Asm + ((wr*4+r)*2+h)*512 + lane*8);
        #pragma unroll
        for (int c = 0; c < 4; ++c)
            #pragma unroll
            for (int h = 0; h < 2; ++h)
                bfr[c][h] = *(const bf16x8*)(Bsm + ((wc*4+c)*2+h)*512 + lane*8);
        __syncthreads();
        if (ki < 7) issue((ki + 1) * 64);
        #pragma unroll
        for (int h = 0; h < 2; ++h)
            #pragma unroll
            for (int r = 0; r < 4; ++r)
                #pragma unroll
                for (int c = 0; c < 4; ++c)
                    acc[r][c] = __builtin_amdgcn_mfma_f32_16x16x32_bf16(af[r][h], bfr[c][h], acc[r][c], 0,0,0);
    }

    // stats inline: mu = 1 - rowsum/N ; inv2s2 = 1/(2*(q - rowsum^2/N)/(N-1))
    int labj[4]; float muj[4], isj[4];
    #pragma unroll
    for (int c = 0; c < 4; ++c) {
        const int j = C0 + wc*64 + c*16 + f_l;
        labj[c] = labels[j];
        const float rs = rowsum[j], qq = q[j];
        const float mean = rs * (1.0f / NTOT);
        const float var  = (qq - rs * mean) * (1.0f / (NTOT - 1));
        muj[c] = 1.0f - mean;
        isj[c] = 1.0f / (2.0f * var);
    }
    float local = 0.f;
    #pragma unroll
    for (int r = 0; r < 4; ++r) {
        const int ib = R0 + wr*64 + r*16 + q_l*4;
        int   li[4]; float mi[4], vi[4];
        #pragma unroll
        for (int u = 0; u < 4; ++u) {
            const int i = ib + u;
            li[u] = labels[i];
            const float rs = rowsum[i], qq = q[i];
            const float mean = rs * (1.0f / NTOT);
            const float var  = (qq - rs * mean) * (1.0f / (NTOT - 1));
            mi[u] = 1.0f - mean;
            vi[u] = 1.0f / (2.0f * var);
        }
        #pragma unroll
        for (int u = 0; u < 4; ++u) {
            #pragma unroll
            for (int c = 0; c < 4; ++c) {
                const float s  = acc[r][c][u];
                const float d  = 1.0f - s;
                const float dj = d - muj[c];
                float e = __expf(s * TEMP_INV + dj * dj * isj[c]);
                if (bi != bj) {                    // wave-uniform
                    const float di = d - mi[u];
                    e += __expf(s * TEMP_INV + di * di * vi[u]);
                }
                local += (li[u] != labj[c]) ? e : 0.f;
            }
        }
    }
    #pragma unroll
    for (int off = 1; off < 64; off <<= 1) local += __shfl_xor(local, off);
    if (lane == 0) redbuf[wave] = local;
    __syncthreads();
    if (tid == 0)
        atomicAdd(neg_acc, (double)(redbuf[0] + redbuf[1] + redbuf[2] + redbuf[3]));
}

// ---------------- positive pairs ----------------
__global__ __launch_bounds__(256)
void pos_k(const __hip_bfloat16* __restrict__ zn, const int* __restrict__ labels,
           double* __restrict__ pos_acc)
{
    const int wave = threadIdx.x >> 6, lane = threadIdx.x & 63;
    const int pair = blockIdx.x * 4 + wave;
    const __hip_bfloat16* a = zn + (size_t)pair * DIM;
    const __hip_bfloat16* b = zn + (size_t)(pair + BATCH) * DIM;
    float s = 0.f;
    for (int k = lane; k < DIM; k += 64)
        s += __bfloat162float(a[k]) * __bfloat162float(b[k]);
    #pragma unroll
    for (int off = 32; off > 0; off >>= 1) s += __shfl_down(s, off);
    if (lane == 0 && labels[pair] == labels[pair + BATCH])
        atomicAdd(pos_acc, (double)__expf(s * TEMP_INV));
}

// ---------------- final loss ----------------
__global__ void loss_k(const double* __restrict__ accs, float* __restrict__ out)
{
    const double neg = accs[0], pos = accs[1];
    out[0] = (float)(-log(pos / (pos + neg)));
}

extern "C" void kernel_launch(void* const* d_in, const int* in_sizes, int n_in,
                              void* d_out, int out_size, void* d_ws, size_t ws_size,
                              hipStream_t stream)
{
    const float* z      = (const float*)d_in[0];
    const int*   labels = (const int*)d_in[1];
    float* out = (float*)d_out;

    char* ws = (char*)d_ws;
    __hip_bfloat16* zn  = (__hip_bfloat16*)ws;                       // 8 MiB
    const size_t ZN_BYTES = (size_t)NTOT * DIM * 2;
    __hip_bfloat16* znT = (__hip_bfloat16*)(ws + ZN_BYTES);          // 8 MiB
    char* zbase = ws + 2 * ZN_BYTES;
    float*  S      = (float*)zbase;                                  // 512
    float*  rowsum = S + DIM;                                        // 8192
    float*  q      = rowsum + NTOT;                                  // 8192
    double* accs   = (double*)(q + NTOT);                            // 2 (8B aligned)
    float*  G32    = (float*)((char*)accs + 16);                     // 1 MiB
    __hip_bfloat16* Gbf = (__hip_bfloat16*)(G32 + DIM * DIM);        // 512 KiB
    const size_t ZERO_BYTES = (DIM + 2 * NTOT) * sizeof(float) + 16
                            + (size_t)DIM * DIM * sizeof(float);

    hipMemsetAsync(S, 0, ZERO_BYTES, stream);

    normalize_k<<<NTOT / 4, 256, 0, stream>>>(z, zn);
    trans_colsum_k<<<dim3(NTOT / 64, DIM / 64), 256, 0, stream>>>(zn, znT, S);
    gram_k<<<dim3(4, 4, 16), 256, 0, stream>>>(znT, G32);
    convg_k<<<DIM * DIM / 4 / 256, 256, 0, stream>>>(G32, Gbf);
    qrow_k<<<dim3(DIM / 128, NTOT / 128), 256, 0, stream>>>(zn, Gbf, S, rowsum, q);
    sim_neg_k<<<NBLK, 256, 0, stream>>>(zn, labels, rowsum, q, accs);
    pos_k<<<BATCH / 4, 256, 0, stream>>>(zn, labels, accs + 1);
    loss_k<<<1, 1, 0, stream>>>(accs, out);
}

// Round 7
// 235.527 us; speedup vs baseline: 1.0156x; 1.0156x over previous
//
#include <hip/hip_runtime.h>
#include <hip/hip_bf16.h>
#include <math.h>

#define NTOT  8192
#define DIM   512
#define BATCH (NTOT/2)
#define TEMP_INV 5.0f   // 1/0.2
#define TTILE 64                      // 8192 / 128 tiles per side
#define NBLK  (TTILE*(TTILE+1)/2)     // 2080 upper-triangle tiles
#define KCH   16                      // gram split-K chunks (512 each)

typedef __attribute__((ext_vector_type(8))) short bf16x8;
typedef __attribute__((ext_vector_type(4))) float f32x4;

// column-major triangle decode: t = bj*(bj+1)/2 + bi, bi <= bj.
__device__ __forceinline__ void decode_tile(int t, int& bi, int& bj)
{
    int b = (int)((sqrtf(8.0f * (float)t + 1.0f) - 1.0f) * 0.5f);
    while ((b + 1) * (b + 2) / 2 <= t) ++b;
    while (b * (b + 1) / 2 > t)       --b;
    bj = b;
    bi = t - b * (b + 1) / 2;
}

__device__ __forceinline__ unsigned int pack_bf16_2(float a, float b)
{
    __hip_bfloat16 ha = __float2bfloat16(a), hb = __float2bfloat16(b);
    unsigned short ua, ub;
    __builtin_memcpy(&ua, &ha, 2); __builtin_memcpy(&ub, &hb, 2);
    return (unsigned int)ua | ((unsigned int)ub << 16);
}
__device__ __forceinline__ float us2f(unsigned short u)
{
    __hip_bfloat16 h; __builtin_memcpy(&h, &u, 2);
    return __bfloat162float(h);
}

// ---------------- normalize: one wave per row ----------------
__global__ __launch_bounds__(256)
void normalize_k(const float* __restrict__ z, __hip_bfloat16* __restrict__ zn)
{
    const int lane = threadIdx.x & 63, wave = threadIdx.x >> 6;
    const int row  = blockIdx.x * 4 + wave;
    const float4* zr = (const float4*)(z + (size_t)row * DIM);
    const float4 a = zr[lane];
    const float4 b = zr[lane + 64];
    float ss = a.x*a.x + a.y*a.y + a.z*a.z + a.w*a.w
             + b.x*b.x + b.y*b.y + b.z*b.z + b.w*b.w;
    #pragma unroll
    for (int off = 1; off < 64; off <<= 1) ss += __shfl_xor(ss, off);
    const float inv = 1.0f / fmaxf(sqrtf(ss), 1e-12f);
    uint2* zo = (uint2*)(zn + (size_t)row * DIM);
    uint2 o0, o1;
    o0.x = pack_bf16_2(a.x * inv, a.y * inv);
    o0.y = pack_bf16_2(a.z * inv, a.w * inv);
    o1.x = pack_bf16_2(b.x * inv, b.y * inv);
    o1.y = pack_bf16_2(b.z * inv, b.w * inv);
    zo[lane]      = o0;
    zo[lane + 64] = o1;
}

// ---------------- transpose zn -> znT (512 x 8192) + column sums S ----------------
__global__ __launch_bounds__(256)
void trans_colsum_k(const __hip_bfloat16* __restrict__ zn,
                    __hip_bfloat16* __restrict__ znT,
                    float* __restrict__ S)
{
    __shared__ unsigned short tile[64][72];   // +8 pad breaks bank alignment
    const int t  = threadIdx.x;
    const int r0 = blockIdx.x * 64, c0 = blockIdx.y * 64;
    #pragma unroll
    for (int v = 0; v < 2; ++v) {
        const int r  = v * 32 + (t >> 3);
        const int cb = (t & 7) * 8;
        *(bf16x8*)&tile[r][cb] = *(const bf16x8*)(zn + (size_t)(r0 + r) * DIM + c0 + cb);
    }
    __syncthreads();
    #pragma unroll
    for (int v = 0; v < 2; ++v) {
        const int cl = v * 32 + (t >> 3);     // local column (dim index)
        const int rb = (t & 7) * 8;           // local row base
        bf16x8 w;
        float s = 0.f;
        #pragma unroll
        for (int e = 0; e < 8; ++e) {
            const unsigned short u = tile[rb + e][cl];
            w[e] = (short)u;
            s += us2f(u);
        }
        *(bf16x8*)(znT + (size_t)(c0 + cl) * NTOT + r0 + rb) = w;
        s += __shfl_xor(s, 1, 8);
        s += __shfl_xor(s, 2, 8);
        s += __shfl_xor(s, 4, 8);
        if ((t & 7) == 0) atomicAdd(&S[c0 + cl], s);
    }
}

// ---------------- Gram partials: Gpart[z] = znT(:,zchunk) znT(:,zchunk)^T ----------------
// plain coalesced stores, NO atomics; convg_k sums the KCH slices.
__global__ __launch_bounds__(256, 4)
void gram_k(const __hip_bfloat16* __restrict__ znT, float* __restrict__ Gpart)
{
    __shared__ unsigned short Asm[8192];   // 16 KB: 128 rows x 64 k, frag order
    __shared__ unsigned short Bsm[8192];
    const int tid = threadIdx.x, wave = tid >> 6, lane = tid & 63;
    const int f_l = lane & 15, q_l = lane >> 4;
    const int a0 = blockIdx.x * 128, b0 = blockIdx.y * 128;
    const int kbase = blockIdx.z * 512;
    const int wr = wave >> 1, wc = wave & 1;

    auto issue = [&](int k0) {
        #pragma unroll
        for (int s4 = 0; s4 < 4; ++s4) {
            const int seg = wave * 4 + s4, rowseg = seg >> 1, kh = seg & 1;
            const int gk  = kbase + k0 + kh * 32 + q_l * 8;
            const __hip_bfloat16* ga = znT + (size_t)(a0 + rowseg * 16 + f_l) * NTOT + gk;
            const __hip_bfloat16* gb = znT + (size_t)(b0 + rowseg * 16 + f_l) * NTOT + gk;
            __builtin_amdgcn_global_load_lds(
                (const __attribute__((address_space(1))) unsigned int*)ga,
                (__attribute__((address_space(3))) unsigned int*)(Asm + seg * 512 + lane * 8), 16, 0, 0);
            __builtin_amdgcn_global_load_lds(
                (const __attribute__((address_space(1))) unsigned int*)gb,
                (__attribute__((address_space(3))) unsigned int*)(Bsm + seg * 512 + lane * 8), 16, 0, 0);
        }
    };

    f32x4 acc[4][4];
    #pragma unroll
    for (int r = 0; r < 4; ++r)
        #pragma unroll
        for (int c = 0; c < 4; ++c) acc[r][c] = (f32x4){0.f,0.f,0.f,0.f};

    issue(0);
    for (int ki = 0; ki < 8; ++ki) {
        __syncthreads();
        bf16x8 af[4][2], bfr[4][2];
        #pragma unroll
        for (int r = 0; r < 4; ++r)
            #pragma unroll
            for (int h = 0; h < 2; ++h)
                af[r][h] = *(const bf16x8*)(Asm + ((wr*4+r)*2+h)*512 + lane*8);
        #pragma unroll
        for (int c = 0; c < 4; ++c)
            #pragma unroll
            for (int h = 0; h < 2; ++h)
                bfr[c][h] = *(const bf16x8*)(Bsm + ((wc*4+c)*2+h)*512 + lane*8);
        __syncthreads();
        if (ki < 7) issue((ki + 1) * 64);
        #pragma unroll
        for (int h = 0; h < 2; ++h)
            #pragma unroll
            for (int r = 0; r < 4; ++r)
                #pragma unroll
                for (int c = 0; c < 4; ++c)
                    acc[r][c] = __builtin_amdgcn_mfma_f32_16x16x32_bf16(af[r][h], bfr[c][h], acc[r][c], 0,0,0);
    }
    float* dst = Gpart + (size_t)blockIdx.z * DIM * DIM;
    #pragma unroll
    for (int r = 0; r < 4; ++r)
        #pragma unroll
        for (int c = 0; c < 4; ++c)
            #pragma unroll
            for (int u = 0; u < 4; ++u)
                dst[(size_t)(a0 + wr*64 + r*16 + q_l*4 + u) * DIM
                    + b0 + wc*64 + c*16 + f_l] = acc[r][c][u];
}

// ---------------- sum KCH Gram slices -> bf16 G ----------------
__global__ __launch_bounds__(256)
void convg_k(const float* __restrict__ Gpart, __hip_bfloat16* __restrict__ Gbf)
{
    const int idx = blockIdx.x * 256 + threadIdx.x;   // float4 index, 65536 total
    float4 s = {0.f, 0.f, 0.f, 0.f};
    #pragma unroll
    for (int z = 0; z < KCH; ++z) {
        const float4 g = ((const float4*)Gpart)[(size_t)z * (DIM * DIM / 4) + idx];
        s.x += g.x; s.y += g.y; s.z += g.z; s.w += g.w;
    }
    uint2 o; o.x = pack_bf16_2(s.x, s.y); o.y = pack_bf16_2(s.z, s.w);
    ((uint2*)Gbf)[idx] = o;
}

// ---------------- Y = Zn * G (row-major fp32 store, no epilogue gather) ----------------
__global__ __launch_bounds__(256, 4)
void qrow_k(const __hip_bfloat16* __restrict__ zn,
            const __hip_bfloat16* __restrict__ Gbf,
            float* __restrict__ Y)
{
    __shared__ unsigned short Asm[8192];
    __shared__ unsigned short Bsm[8192];
    const int tid = threadIdx.x, wave = tid >> 6, lane = tid & 63;
    const int f_l = lane & 15, q_l = lane >> 4;
    const int C0 = blockIdx.x * 128;   // dim slab (rows of G)
    const int R0 = blockIdx.y * 128;   // zn rows
    const int wr = wave >> 1, wc = wave & 1;

    auto issue = [&](int k0) {
        #pragma unroll
        for (int s4 = 0; s4 < 4; ++s4) {
            const int seg = wave * 4 + s4, rowseg = seg >> 1, kh = seg & 1;
            const int gk  = k0 + kh * 32 + q_l * 8;
            const __hip_bfloat16* ga = zn  + (size_t)(R0 + rowseg * 16 + f_l) * DIM + gk;
            const __hip_bfloat16* gb = Gbf + (size_t)(C0 + rowseg * 16 + f_l) * DIM + gk;
            __builtin_amdgcn_global_load_lds(
                (const __attribute__((address_space(1))) unsigned int*)ga,
                (__attribute__((address_space(3))) unsigned int*)(Asm + seg * 512 + lane * 8), 16, 0, 0);
            __builtin_amdgcn_global_load_lds(
                (const __attribute__((address_space(1))) unsigned int*)gb,
                (__attribute__((address_space(3))) unsigned int*)(Bsm + seg * 512 + lane * 8), 16, 0, 0);
        }
    };

    f32x4 acc[4][4];
    #pragma unroll
    for (int r = 0; r < 4; ++r)
        #pragma unroll
        for (int c = 0; c < 4; ++c) acc[r][c] = (f32x4){0.f,0.f,0.f,0.f};

    issue(0);
    for (int ki = 0; ki < 8; ++ki) {
        __syncthreads();
        bf16x8 af[4][2], bfr[4][2];
        #pragma unroll
        for (int r = 0; r < 4; ++r)
            #pragma unroll
            for (int h = 0; h < 2; ++h)
                af[r][h] = *(const bf16x8*)(Asm + ((wr*4+r)*2+h)*512 + lane*8);
        #pragma unroll
        for (int c = 0; c < 4; ++c)
            #pragma unroll
            for (int h = 0; h < 2; ++h)
                bfr[c][h] = *(const bf16x8*)(Bsm + ((wc*4+c)*2+h)*512 + lane*8);
        __syncthreads();
        if (ki < 7) issue((ki + 1) * 64);
        #pragma unroll
        for (int h = 0; h < 2; ++h)
            #pragma unroll
            for (int r = 0; r < 4; ++r)
                #pragma unroll
                for (int c = 0; c < 4; ++c)
                    acc[r][c] = __builtin_amdgcn_mfma_f32_16x16x32_bf16(af[r][h], bfr[c][h], acc[r][c], 0,0,0);
    }
    #pragma unroll
    for (int r = 0; r < 4; ++r)
        #pragma unroll
        for (int c = 0; c < 4; ++c)
            #pragma unroll
            for (int u = 0; u < 4; ++u)
                Y[(size_t)(R0 + wr*64 + r*16 + q_l*4 + u) * DIM
                  + C0 + wc*64 + c*16 + f_l] = acc[r][c][u];
}

// ---------------- per-row stats: mu_i, inv2s2_i from zn.S and zn.Y ----------------
__global__ __launch_bounds__(256)
void rowstat_k(const __hip_bfloat16* __restrict__ zn,
               const float* __restrict__ Y,
               const float* __restrict__ S,
               float* __restrict__ mu_d,
               float* __restrict__ is2)
{
    const int lane = threadIdx.x & 63, wave = threadIdx.x >> 6;
    const int row  = blockIdx.x * 4 + wave;
    const bf16x8 zv = *(const bf16x8*)(zn + (size_t)row * DIM + lane * 8);
    const float4 y0 = *(const float4*)(Y + (size_t)row * DIM + lane * 8);
    const float4 y1 = *(const float4*)(Y + (size_t)row * DIM + lane * 8 + 4);
    const float4 s0 = *(const float4*)(S + lane * 8);
    const float4 s1 = *(const float4*)(S + lane * 8 + 4);
    float zf[8];
    #pragma unroll
    for (int e = 0; e < 8; ++e) zf[e] = us2f((unsigned short)zv[e]);
    float rs = zf[0]*s0.x + zf[1]*s0.y + zf[2]*s0.z + zf[3]*s0.w
             + zf[4]*s1.x + zf[5]*s1.y + zf[6]*s1.z + zf[7]*s1.w;
    float qq = zf[0]*y0.x + zf[1]*y0.y + zf[2]*y0.z + zf[3]*y0.w
             + zf[4]*y1.x + zf[5]*y1.y + zf[6]*y1.z + zf[7]*y1.w;
    #pragma unroll
    for (int off = 1; off < 64; off <<= 1) {
        rs += __shfl_xor(rs, off);
        qq += __shfl_xor(qq, off);
    }
    if (lane == 0) {
        const float mean = rs * (1.0f / NTOT);
        const float var  = (qq - rs * mean) * (1.0f / (NTOT - 1));
        mu_d[row] = 1.0f - mean;
        is2[row]  = 1.0f / (2.0f * var);
    }
}

// ---------------- sim pass: single triangle MFMA pass, neg-sum in epilogue ----------------
__global__ __launch_bounds__(256, 4)
void sim_neg_k(const __hip_bfloat16* __restrict__ zn,
               const int*   __restrict__ labels,
               const float* __restrict__ mu_d,
               const float* __restrict__ is2,
               double* __restrict__ neg_acc)
{
    __shared__ unsigned short Asm[8192];   // 16 KB, frag order
    __shared__ unsigned short Bsm[8192];
    __shared__ float redbuf[4];
    const int tid = threadIdx.x, wave = tid >> 6, lane = tid & 63;
    const int f_l = lane & 15, q_l = lane >> 4;
    int bi, bj;
    decode_tile(blockIdx.x, bi, bj);
    const int R0 = bi * 128, C0 = bj * 128;
    const int wr = wave >> 1, wc = wave & 1;

    auto issue = [&](int k0) {
        #pragma unroll
        for (int s4 = 0; s4 < 4; ++s4) {
            const int seg = wave * 4 + s4, rowseg = seg >> 1, kh = seg & 1;
            const int gk  = k0 + kh * 32 + q_l * 8;
            const __hip_bfloat16* ga = zn + (size_t)(R0 + rowseg * 16 + f_l) * DIM + gk;
            const __hip_bfloat16* gb = zn + (size_t)(C0 + rowseg * 16 + f_l) * DIM + gk;
            __builtin_amdgcn_global_load_lds(
                (const __attribute__((address_space(1))) unsigned int*)ga,
                (__attribute__((address_space(3))) unsigned int*)(Asm + seg * 512 + lane * 8), 16, 0, 0);
            __builtin_amdgcn_global_load_lds(
                (const __attribute__((address_space(1))) unsigned int*)gb,
                (__attribute__((address_space(3))) unsigned int*)(Bsm + seg * 512 + lane * 8), 16, 0, 0);
        }
    };

    f32x4 acc[4][4];
    #pragma unroll
    for (int r = 0; r < 4; ++r)
        #pragma unroll
        for (int c = 0; c < 4; ++c) acc[r][c] = (f32x4){0.f,0.f,0.f,0.f};

    issue(0);
    for (int ki = 0; ki < 8; ++ki) {
        __syncthreads();
        bf16x8 af[4][2], bfr[4][2];
        #pragma unroll
        for (int r = 0; r < 4; ++r)
            #pragma unroll
            for (int h = 0; h < 2; ++h)
                af[r][h] = *(const bf16x8*)(Asm + ((wr*4+r)*2+h)*512 + lane*8);
        #pragma unroll
        for (int c = 0; c < 4; ++c)
            #pragma unroll
            for (int h = 0; h < 2; ++h)
                bfr[c][h] = *(const bf16x8*)(Bsm + ((wc*4+c)*2+h)*512 + lane*8);
        __syncthreads();
        if (ki < 7) issue((ki + 1) * 64);
        #pragma unroll
        for (int h = 0; h < 2; ++h)
            #pragma unroll
            for (int r = 0; r < 4; ++r)
                #pragma unroll
                for (int c = 0; c < 4; ++c)
                    acc[r][c] = __builtin_amdgcn_mfma_f32_16x16x32_bf16(af[r][h], bfr[c][h], acc[r][c], 0,0,0);
    }

    int labj[4]; float muj[4], isj[4];
    #pragma unroll
    for (int c = 0; c < 4; ++c) {
        const int j = C0 + wc*64 + c*16 + f_l;
        labj[c] = labels[j]; muj[c] = mu_d[j]; isj[c] = is2[j];
    }
    float local = 0.f;
    #pragma unroll
    for (int r = 0; r < 4; ++r) {
        const int ib = R0 + wr*64 + r*16 + q_l*4;
        int   li[4]; float mi[4], vi[4];
        #pragma unroll
        for (int u = 0; u < 4; ++u) {
            li[u] = labels[ib + u];
            mi[u] = mu_d[ib + u];
            vi[u] = is2[ib + u];
        }
        #pragma unroll
        for (int u = 0; u < 4; ++u) {
            #pragma unroll
            for (int c = 0; c < 4; ++c) {
                const float s  = acc[r][c][u];
                const float d  = 1.0f - s;
                const float dj = d - muj[c];
                float e = __expf(s * TEMP_INV + dj * dj * isj[c]);
                if (bi != bj) {                    // wave-uniform
                    const float di = d - mi[u];
                    e += __expf(s * TEMP_INV + di * di * vi[u]);
                }
                local += (li[u] != labj[c]) ? e : 0.f;
            }
        }
    }
    #pragma unroll
    for (int off = 1; off < 64; off <<= 1) local += __shfl_xor(local, off);
    if (lane == 0) redbuf[wave] = local;
    __syncthreads();
    if (tid == 0)
        atomicAdd(neg_acc, (double)(redbuf[0] + redbuf[1] + redbuf[2] + redbuf[3]));
}

// ---------------- positive pairs ----------------
__global__ __launch_bounds__(256)
void pos_k(const __hip_bfloat16* __restrict__ zn, const int* __restrict__ labels,
           double* __restrict__ pos_acc)
{
    const int wave = threadIdx.x >> 6, lane = threadIdx.x & 63;
    const int pair = blockIdx.x * 4 + wave;
    const __hip_bfloat16* a = zn + (size_t)pair * DIM;
    const __hip_bfloat16* b = zn + (size_t)(pair + BATCH) * DIM;
    float s = 0.f;
    for (int k = lane; k < DIM; k += 64)
        s += __bfloat162float(a[k]) * __bfloat162float(b[k]);
    #pragma unroll
    for (int off = 32; off > 0; off >>= 1) s += __shfl_down(s, off);
    if (lane == 0 && labels[pair] == labels[pair + BATCH])
        atomicAdd(pos_acc, (double)__expf(s * TEMP_INV));
}

// ---------------- final loss ----------------
__global__ void loss_k(const double* __restrict__ accs, float* __restrict__ out)
{
    const double neg = accs[0], pos = accs[1];
    out[0] = (float)(-log(pos / (pos + neg)));
}

extern "C" void kernel_launch(void* const* d_in, const int* in_sizes, int n_in,
                              void* d_out, int out_size, void* d_ws, size_t ws_size,
                              hipStream_t stream)
{
    const float* z      = (const float*)d_in[0];
    const int*   labels = (const int*)d_in[1];
    float* out = (float*)d_out;

    char* ws = (char*)d_ws;
    __hip_bfloat16* zn  = (__hip_bfloat16*)ws;                       // 8 MiB
    const size_t ZN_BYTES = (size_t)NTOT * DIM * 2;
    __hip_bfloat16* znT = (__hip_bfloat16*)(ws + ZN_BYTES);          // 8 MiB
    char* p = ws + 2 * ZN_BYTES;
    float*  S      = (float*)p;                 p += DIM * sizeof(float);      // 2 KB
    double* accs   = (double*)p;                p += 2 * sizeof(double);       // 16 B (memset with S)
    float*  mu_d   = (float*)p;                 p += NTOT * sizeof(float);
    float*  is2    = (float*)p;                 p += NTOT * sizeof(float);
    __hip_bfloat16* Gbf = (__hip_bfloat16*)p;   p += (size_t)DIM * DIM * 2;    // 512 KB
    float*  Y      = (float*)p;                 p += (size_t)NTOT * DIM * 4;   // 16 MB
    float*  Gpart  = (float*)p;                 // KCH MB (16 MB)

    hipMemsetAsync(S, 0, DIM * sizeof(float) + 2 * sizeof(double), stream);

    normalize_k<<<NTOT / 4, 256, 0, stream>>>(z, zn);
    trans_colsum_k<<<dim3(NTOT / 64, DIM / 64), 256, 0, stream>>>(zn, znT, S);
    gram_k<<<dim3(4, 4, KCH), 256, 0, stream>>>(znT, Gpart);
    convg_k<<<DIM * DIM / 4 / 256, 256, 0, stream>>>(Gpart, Gbf);
    qrow_k<<<dim3(DIM / 128, NTOT / 128), 256, 0, stream>>>(zn, Gbf, Y);
    rowstat_k<<<NTOT / 4, 256, 0, stream>>>(zn, Y, S, mu_d, is2);
    sim_neg_k<<<NBLK, 256, 0, stream>>>(zn, labels, mu_d, is2, accs);
    pos_k<<<BATCH / 4, 256, 0, stream>>>(zn, labels, accs + 1);
    loss_k<<<1, 1, 0, stream>>>(accs, out);
}